// Round 12
// baseline (107.428 us; speedup 1.0000x reference)
//
#include <hip/hip_runtime.h>

// RelativePositionEncoding — out 512 MiB fp32, HBM-write-bound.
// R12: R11 with PRIME 4 -> 2. Theory: the residual ramp cost is the
// prime-phase per-lane W gather from global (L1/L2 vector path) colliding
// with the store ramp: R9=100MB->112.5us, R10/R11=50MB->105.6us. PRIME=2
// cuts it to 25MB while still covering the staged-load flight before the
// LDS commit+sync. Everything else identical to R11 (256x1024, 1 blk/CU,
// 128 iters, prime-overlap staging).
// Decode: 101-103 -> theory confirmed, push further; flat -> ROOFLINE.

typedef float f4 __attribute__((ext_vector_type(4)));

constexpr int ROWS = 136;      // 65 rel_pos | 65 rel_token | 1 entity | 5 rel_chain
constexpr int THREADS = 1024;
constexpr int GRID = 256;      // 262,144 threads x 128 f4 stores
constexpr int ITERS = 128;
constexpr int PRIME = 2;       // iterations served from global W before LDS commit

__global__ __launch_bounds__(THREADS)
void relpos_kernel(const int* __restrict__ asym,
                   const int* __restrict__ resid,
                   const int* __restrict__ ent,
                   const int* __restrict__ tok,
                   const int* __restrict__ sym,
                   const float* __restrict__ W,
                   f4* __restrict__ outv)
{
    __shared__ f4 sW[ROWS * 32];               // 69,632 B, 1 block/CU
    const int tid = threadIdx.x;
    const f4* Wv = reinterpret_cast<const f4*>(W);   // W as [136*32] f4

    // ---- issue W->reg staging loads NOW; they fly under the prime phase ----
    f4 st[4];                                  // 4096 of 4352 f4
    #pragma unroll
    for (int k = 0; k < 4; ++k)
        st[k] = Wv[tid + k * 1024];
    f4 st8;                                    // remaining 256 f4
    if (tid < 256) st8 = Wv[4096 + tid];

    // ---- decomposition: c4 fixed, j fixed, i = i0 + 8*it ----
    const int t  = blockIdx.x * THREADS + tid;
    const int c4 = t & 31;
    const int p0 = t >> 5;
    const int j  = p0 & 1023;
    const int i0 = p0 >> 10;                   // in [0,8)

    const int aj = asym[j];
    const int rj = resid[j];
    const int ej = ent[j];
    const int tj = tok[j];
    const int sj = sym[j];

    const f4 vE = Wv[130 * 32 + c4];           // entity row: reg for whole kernel

    size_t oidx = (size_t)t;

    // ---- PRIME: it = 0..1 with W from global; stores start immediately ----
    #pragma unroll
    for (int it = 0; it < PRIME; ++it) {
        const int i  = i0 + 8 * it;
        const int ai = asym[i];
        const int ri = resid[i];
        const int ei = ent[i];
        const int ti = tok[i];
        const int si = sym[i];

        const bool sc = (ai == aj);
        const bool sr = (ri == rj);

        int dres = min(max(rj - ri + 32, 0), 64);
        int dtok = min(max(tj - ti + 32, 0), 64);
        int dch  = min(max(sj - si + 2, 0), 4);
        if (sc)        { dres = 64; dch = 4; }
        if (sc || sr)  { dtok = 64; }
        const float se = (ei == ej) ? 1.0f : 0.0f;

        const f4 v0 = Wv[dres * 32 + c4];
        const f4 v1 = Wv[(65 + dtok) * 32 + c4];
        const f4 v3 = Wv[(131 + dch) * 32 + c4];

        f4 r;
        r.x = fmaf(se, vE.x, v0.x + v1.x) + v3.x;
        r.y = fmaf(se, vE.y, v0.y + v1.y) + v3.y;
        r.z = fmaf(se, vE.z, v0.z + v1.z) + v3.z;
        r.w = fmaf(se, vE.w, v0.w + v1.w) + v3.w;

        outv[oidx] = r;
        oidx += (size_t)GRID * THREADS;        // 262,144 f4 = 4 MiB
    }

    // ---- commit staged W to LDS, single sync ----
    #pragma unroll
    for (int k = 0; k < 4; ++k)
        sW[tid + k * 1024] = st[k];
    if (tid < 256) sW[4096 + tid] = st8;
    __syncthreads();

    // ---- MAIN: it = 2..127 from LDS (identical math) ----
    #pragma unroll 4
    for (int it = PRIME; it < ITERS; ++it) {
        const int i  = i0 + 8 * it;
        const int ai = asym[i];
        const int ri = resid[i];
        const int ei = ent[i];
        const int ti = tok[i];
        const int si = sym[i];

        const bool sc = (ai == aj);
        const bool sr = (ri == rj);

        int dres = min(max(rj - ri + 32, 0), 64);
        int dtok = min(max(tj - ti + 32, 0), 64);
        int dch  = min(max(sj - si + 2, 0), 4);
        if (sc)        { dres = 64; dch = 4; }
        if (sc || sr)  { dtok = 64; }
        const float se = (ei == ej) ? 1.0f : 0.0f;

        const f4 v0 = sW[dres * 32 + c4];
        const f4 v1 = sW[(65 + dtok) * 32 + c4];
        const f4 v3 = sW[(131 + dch) * 32 + c4];

        f4 r;
        r.x = fmaf(se, vE.x, v0.x + v1.x) + v3.x;
        r.y = fmaf(se, vE.y, v0.y + v1.y) + v3.y;
        r.z = fmaf(se, vE.z, v0.z + v1.z) + v3.z;
        r.w = fmaf(se, vE.w, v0.w + v1.w) + v3.w;

        outv[oidx] = r;
        oidx += (size_t)GRID * THREADS;
    }
}

extern "C" void kernel_launch(void* const* d_in, const int* in_sizes, int n_in,
                              void* d_out, int out_size, void* d_ws, size_t ws_size,
                              hipStream_t stream) {
    const int*   asym  = (const int*)  d_in[0];
    const int*   resid = (const int*)  d_in[1];
    const int*   ent   = (const int*)  d_in[2];
    const int*   tok   = (const int*)  d_in[3];
    const int*   sym   = (const int*)  d_in[4];
    const float* W     = (const float*)d_in[5];
    f4* outv = (f4*)d_out;

    relpos_kernel<<<GRID, THREADS, 0, stream>>>(asym, resid, ent, tok, sym, W, outv);
}